// Round 10
// baseline (1094.634 us; speedup 1.0000x reference)
//
#include <hip/hip_runtime.h>
#include <hip/hip_cooperative_groups.h>

namespace cg = cooperative_groups;

typedef unsigned int u32;
typedef unsigned short u16;
typedef unsigned char u8;
typedef __attribute__((ext_vector_type(8))) short bf16x8;
typedef __attribute__((ext_vector_type(4))) float f32x4;

#define FLAG_DELTA 2e-2f

// ---------- Threefry-2x32, 20 rounds (matches jax._src.prng.threefry2x32) ----
__host__ __device__ static inline void tf2x32(u32 k0, u32 k1, u32 x0, u32 x1,
                                              u32* o0, u32* o1)
{
  const u32 ks2 = k0 ^ k1 ^ 0x1BD11BDAu;
#define TF_R(v, r) (((v) << (r)) | ((v) >> (32 - (r))))
#define TF_RND(r) do { x0 += x1; x1 = TF_R(x1, r); x1 ^= x0; } while (0);
  x0 += k0; x1 += k1;
  TF_RND(13) TF_RND(15) TF_RND(26) TF_RND(6)
  x0 += k1;  x1 += ks2 + 1u;
  TF_RND(17) TF_RND(29) TF_RND(16) TF_RND(24)
  x0 += ks2; x1 += k0 + 2u;
  TF_RND(13) TF_RND(15) TF_RND(26) TF_RND(6)
  x0 += k0;  x1 += k1 + 3u;
  TF_RND(17) TF_RND(29) TF_RND(16) TF_RND(24)
  x0 += k1;  x1 += ks2 + 4u;
  TF_RND(13) TF_RND(15) TF_RND(26) TF_RND(6)
  x0 += ks2; x1 += k0 + 5u;
  *o0 = x0; *o1 = x1;
#undef TF_RND
#undef TF_R
}

__device__ static inline u16 f2bf(float f) {
  u32 u = __float_as_uint(f);
  return (u16)((u + 0x7FFFu + ((u >> 16) & 1u)) >> 16);
}

// ---------- fused pipeline: gate+split | spikes | LIF(+inline fix) | combine -
// 512 blocks x 256 thr, 2 blocks/CU co-resident ((256,2): 256-reg budget so
// the LIF phase's ~100 live values stay in ARCH VGPRs - no accvgpr churn,
// which was R7-R9's 10x stall). All fp math bit-identical to passing rounds.
__global__ __launch_bounds__(256, 2) void k_fused(
    const float* __restrict__ q, const float* __restrict__ gbias,
    const float* __restrict__ temp, const float* __restrict__ win,
    const float* __restrict__ ex, const float* __restrict__ gk,
    float* __restrict__ out,
    u16* __restrict__ spk, float* __restrict__ rates,
    float* __restrict__ gateo, u16* __restrict__ wsp,
    u8* __restrict__ cnt, float* __restrict__ ext,
    u32 bk0, u32 bk1)
{
  cg::grid_group grid = cg::this_grid();
  const int bid = blockIdx.x, tid = threadIdx.x;

  __shared__ union SM {
    float qs[4][1024];     // gate staging
    float tile[64][65];    // split staging
  } sm;

  // ===== P0: gate (blocks 0..63, 4 b each) | expert split (blocks 64..319) ==
  if (bid < 64) {
    const int b4 = bid * 4;
#pragma unroll
    for (int r = 0; r < 4; ++r) {
      const float4 qv = *(const float4*)(q + (size_t)(b4 + r) * 1024 + tid * 4);
      *(float4*)(&sm.qs[r][tid * 4]) = qv;
    }
    __syncthreads();
    const int w = tid >> 6, j = tid & 63;
    const int b = b4 + w;
    const float* __restrict__ wc = win + j;
    float bufA[64], bufB[64];
#pragma unroll
    for (int i = 0; i < 64; ++i) bufA[i] = wc[i * 64];
    float c = 0.f;
#pragma unroll
    for (int ch = 0; ch < 8; ++ch) {
#pragma unroll
      for (int i = 0; i < 64; ++i)
        bufB[i] = wc[((2 * ch + 1) * 64 + i) * 64];
#pragma unroll
      for (int i = 0; i < 64; ++i)
        c = __builtin_fmaf(sm.qs[w][2 * ch * 64 + i], bufA[i], c);
      if (ch < 7) {
#pragma unroll
        for (int i = 0; i < 64; ++i)
          bufA[i] = wc[((2 * ch + 2) * 64 + i) * 64];
      }
#pragma unroll
      for (int i = 0; i < 64; ++i)
        c = __builtin_fmaf(sm.qs[w][(2 * ch + 1) * 64 + i], bufB[i], c);
    }
    const float x = c;
    float r;
    if (x >= 0.f) r = __fdiv_rn(1.f, __fadd_rn(1.f, expf(-x)));
    else { const float exv = expf(x); r = __fdiv_rn(exv, __fadd_rn(1.f, exv)); }
    rates[b * 64 + j] = r;

    const int jj = j & 15;
    float l = 0.f;
    for (int dd = 0; dd < 64; ++dd) {
      const float xv = __shfl(x, dd, 64);
      l = __builtin_fmaf(xv, gk[dd * 16 + jj], l);
    }
    l = __fadd_rn(l, gbias[jj]);
    l = __fdiv_rn(l, temp[0]);
    float m = l;
    for (int off = 1; off < 16; off <<= 1) m = fmaxf(m, __shfl_xor(m, off, 16));
    const float p = expf(__fsub_rn(l, m));
    float s = p;
    for (int off = 1; off < 16; off <<= 1) s += __shfl_xor(s, off, 16);
    if (j < 16) gateo[b * 16 + j] = __fdiv_rn(p, s);
  } else if (bid < 320) {
    const int sblk = bid - 64;
    const int e = sblk >> 4, hb = sblk & 15;
    const int tl = tid & 63, tg = tid >> 6;
#pragma unroll
    for (int r = 0; r < 16; ++r) {
      const int d = r * 4 + tg;
      sm.tile[d][tl] = ex[((size_t)e * 64 + d) * 1024 + hb * 64 + tl];
    }
    __syncthreads();
#pragma unroll
    for (int r = 0; r < 16; ++r) {
      const int hl = r * 4 + tg;
      const float wraw = sm.tile[tl][hl];
      const size_t o = ((size_t)e * 1024 + hb * 64 + hl) * 64 + tl;
      wsp[o] = f2bf(wraw * 0.05f);                 // fold leak = DT/TAU
      ext[o] = wraw;                               // raw f32, [E][H][D]
    }
  }
  grid.sync();

  // ===== P1: poisson spikes via threefry (1280 units over 512 blocks) =======
#pragma unroll
  for (int k = 0; k < 3; ++k) {
    const int unit = bid + 512 * k;
    if (unit < 1280) {
      const u32 g = (u32)unit * 256u + (u32)tid;
      u32 o0, o1;
      tf2x32(bk0, bk1, 0u, g, &o0, &o1);           // 64-bit counter (0, g)
      const u32 bits = o0 ^ o1;
      const float r = rates[g & 16383u];
      const float u = __uint_as_float((bits >> 9) | 0x3f800000u) - 1.0f;
      spk[g] = (u < r) ? (u16)0x3F80 : (u16)0;
    }
  }
  grid.sync();

  // ===== P2: LIF scan (1024 tiles over 512 blocks x 2) + inline exact fix ===
  for (int rep = 0; rep < 2; ++rep) {
    const int tau = bid + rep * 512;
    const int hblk = tau & 7, bblk = (tau >> 3) & 7, e = tau >> 6;
    const int w = tid >> 6, lane = tid & 63;
    const int wb = w & 1, wh = w >> 1;
    const int lr = lane & 15, lg = lane >> 4;
    const int b0 = bblk * 32 + wb * 16;
    const int h0 = hblk * 128 + wh * 64;

#define FRAG(NT, KC) (*(const bf16x8*)(wsp + \
    ((size_t)e * 1024 + h0 + (NT) * 16 + lr) * 64 + (KC) * 32 + lg * 8))
    bf16x8 b00 = FRAG(0, 0), b01 = FRAG(0, 1);
    bf16x8 b10 = FRAG(1, 0), b11 = FRAG(1, 1);
    bf16x8 b20 = FRAG(2, 0), b21 = FRAG(2, 1);
    bf16x8 b30 = FRAG(3, 0), b31 = FRAG(3, 1);
#undef FRAG

    f32x4 v0 = (f32x4){0.f, 0.f, 0.f, 0.f};
    f32x4 v1 = v0, v2 = v0, v3 = v0;
    u32 c0 = 0, c1 = 0, c2 = 0, c3 = 0;            // 4 packed byte-counts each
    u32 fl = 0;

    const u16* abase = spk + (size_t)(b0 + lr) * 64 + lg * 8;
    bf16x8 a0 = *(const bf16x8*)(abase);
    bf16x8 a1 = *(const bf16x8*)(abase + 32);

#define PROC(VAL, CW, I, BIT) {                                 \
    const float tt = (VAL) - 0.5f;                              \
    if (__builtin_fabsf(tt) < FLAG_DELTA) fl |= (1u << (BIT));  \
    const bool sp = (tt >= 0.f);                                \
    (CW) += ((u32)sp) << (8 * (I));                             \
    (VAL) = sp ? 0.f : (VAL); }

#define STEP(VV, CW, BL, BH, NT) {                                          \
    f32x4 acc = (VV) * 0.95f;                                               \
    acc = __builtin_amdgcn_mfma_f32_16x16x32_bf16(a0, (BL), acc, 0, 0, 0);  \
    acc = __builtin_amdgcn_mfma_f32_16x16x32_bf16(a1, (BH), acc, 0, 0, 0);  \
    PROC(acc.x, (CW), 0, (NT) * 4 + 0)                                      \
    PROC(acc.y, (CW), 1, (NT) * 4 + 1)                                      \
    PROC(acc.z, (CW), 2, (NT) * 4 + 2)                                      \
    PROC(acc.w, (CW), 3, (NT) * 4 + 3)                                      \
    (VV) = acc; }

    for (int t = 0; t < 20; ++t) {
      const int tn = (t < 19) ? t + 1 : 19;        // prefetch next (clamped)
      const bf16x8 n0 = *(const bf16x8*)(abase + (size_t)tn * 16384);
      const bf16x8 n1 = *(const bf16x8*)(abase + (size_t)tn * 16384 + 32);
      STEP(v0, c0, b00, b01, 0)
      STEP(v1, c1, b10, b11, 1)
      STEP(v2, c2, b20, b21, 2)
      STEP(v3, c3, b30, b31, 3)
      a0 = n0; a1 = n1;
    }
#undef STEP
#undef PROC

    u32 cwa[4] = {c0, c1, c2, c3};

    // inline exact fix for flagged elements (R2-verified chain; ~handful
    // globally, so the divergent cold path is nearly never taken)
    if (fl) {
#pragma unroll
      for (int nt = 0; nt < 4; ++nt)
#pragma unroll
        for (int i = 0; i < 4; ++i)
          if ((fl >> (nt * 4 + i)) & 1u) {
            const int h = h0 + nt * 16 + lr;
            const int b = b0 + lg * 4 + i;
            const float* __restrict__ wp = ext + ((size_t)e * 1024 + h) * 64;
            float v = 0.f;
            u32 c = 0;
            for (int t = 0; t < 20; ++t) {
              const u16* __restrict__ sr = spk + (size_t)(t * 256 + b) * 64;
              float cc = 0.f;
              for (int d = 0; d < 64; ++d)
                cc = __builtin_fmaf(__uint_as_float(((u32)sr[d]) << 16),
                                    wp[d], cc);
              const float nv = __fadd_rn(v, __fmul_rn(__fsub_rn(cc, v), 0.05f));
              if (nv >= 0.5f) { c++; v = 0.f; } else v = nv;
            }
            cwa[nt] = (cwa[nt] & ~(0xFFu << (8 * i))) | (c << (8 * i));
          }
    }

    // C/D layout: col = lane&15 (h), row = (lane>>4)*4 + reg (b)
#pragma unroll
    for (int nt = 0; nt < 4; ++nt) {
      const int h = h0 + nt * 16 + lr;
#pragma unroll
      for (int i = 0; i < 4; ++i) {
        const int b = b0 + lg * 4 + i;
        cnt[((size_t)e * 256 + b) * 1024 + h] = (u8)((cwa[nt] >> (8 * i)) & 0xFFu);
      }
    }
  }
  grid.sync();

  // ===== P3: combine: out[b,h] = ascending-e fma chain of (cnt/20)*p ========
  {
    const int gid = bid * 256 + tid;               // [0, 131072)
    const int b = gid >> 9;
    const int h0 = (gid & 511) * 2;
    float s0 = 0.f, s1 = 0.f;
#pragma unroll
    for (int e = 0; e < 16; ++e) {
      const u16 cv = *(const u16*)(cnt + ((size_t)e * 256 + b) * 1024 + h0);
      const float g = gateo[b * 16 + e];
      s0 = __builtin_fmaf(__fdiv_rn((float)(cv & 0xFFu), 20.f), g, s0);
      s1 = __builtin_fmaf(__fdiv_rn((float)(cv >> 8), 20.f), g, s1);
    }
    float2 o;
    o.x = s0; o.y = s1;
    *(float2*)(out + (size_t)b * 1024 + h0) = o;
  }
}

// ---------- launch ----------------------------------------------------------
extern "C" void kernel_launch(void* const* d_in, const int* in_sizes, int n_in,
                              void* d_out, int out_size, void* d_ws, size_t ws_size,
                              hipStream_t stream)
{
  (void)in_sizes; (void)n_in; (void)out_size; (void)ws_size;
  const float* q     = (const float*)d_in[0];
  const float* gbias = (const float*)d_in[1];
  const float* temp  = (const float*)d_in[2];
  const float* win   = (const float*)d_in[3];
  const float* ex    = (const float*)d_in[4];
  const float* gk    = (const float*)d_in[5];
  float* out = (float*)d_out;

  char* ws = (char*)d_ws;
  u16*  spk   = (u16*)(ws + 0);            // [20][256][64] bf16    655360 B
  float* rates = (float*)(ws + 655360);    // [256][64] f32          65536 B
  float* gateo = (float*)(ws + 720896);    // [256][16] f32          16384 B
  u16*  wsp   = (u16*)(ws + 737280);       // [16][1024][64] bf16  2097152 B
  u8*   cnt   = (u8*)(ws + 2834432);       // [16][256][1024] u8   4194304 B
  float* ext  = (float*)(ws + 7028736);    // [16][1024][64] f32   4194304 B
                                           // total: 11223040 B

  // bern_key = jax.random.split(jax.random.key(0))[1], computed on host
  u32 bk0, bk1;
  tf2x32(0u, 0u, 0u, 1u, &bk0, &bk1);

  void* args[] = {
    (void*)&q, (void*)&gbias, (void*)&temp, (void*)&win, (void*)&ex,
    (void*)&gk, (void*)&out, (void*)&spk, (void*)&rates, (void*)&gateo,
    (void*)&wsp, (void*)&cnt, (void*)&ext, (void*)&bk0, (void*)&bk1
  };
  hipLaunchCooperativeKernel((const void*)k_fused, dim3(512), dim3(256),
                             args, 0, stream);
}

// Round 11
// 196.333 us; speedup vs baseline: 5.5754x; 5.5754x over previous
//
#include <hip/hip_runtime.h>

typedef unsigned int u32;
typedef unsigned short u16;
typedef unsigned char u8;
typedef __attribute__((ext_vector_type(8))) short bf16x8;
typedef __attribute__((ext_vector_type(4))) float f32x4;

#define FLAG_DELTA 2e-2f
#define FLAG_CAP 262144u

// ---------- Threefry-2x32, 20 rounds (matches jax._src.prng.threefry2x32) ----
__host__ __device__ static inline void tf2x32(u32 k0, u32 k1, u32 x0, u32 x1,
                                              u32* o0, u32* o1)
{
  const u32 ks2 = k0 ^ k1 ^ 0x1BD11BDAu;
#define TF_R(v, r) (((v) << (r)) | ((v) >> (32 - (r))))
#define TF_RND(r) do { x0 += x1; x1 = TF_R(x1, r); x1 ^= x0; } while (0);
  x0 += k0; x1 += k1;
  TF_RND(13) TF_RND(15) TF_RND(26) TF_RND(6)
  x0 += k1;  x1 += ks2 + 1u;
  TF_RND(17) TF_RND(29) TF_RND(16) TF_RND(24)
  x0 += ks2; x1 += k0 + 2u;
  TF_RND(13) TF_RND(15) TF_RND(26) TF_RND(6)
  x0 += k0;  x1 += k1 + 3u;
  TF_RND(17) TF_RND(29) TF_RND(16) TF_RND(24)
  x0 += k1;  x1 += ks2 + 4u;
  TF_RND(13) TF_RND(15) TF_RND(26) TF_RND(6)
  x0 += ks2; x1 += k0 + 5u;
  *o0 = x0; *o1 = x1;
#undef TF_RND
#undef TF_R
}

__device__ static inline u16 f2bf(float f) {
  u32 u = __float_as_uint(f);
  return (u16)((u + 0x7FFFu + ((u >> 16) & 1u)) >> 16);
}

// ---------- K0: x = q @ W_in (exact ascending-d chain), 4 b per block -------
__global__ __launch_bounds__(256) void k_gate(
    const float* __restrict__ q, const float* __restrict__ win,
    const float* __restrict__ gbias, const float* __restrict__ temp,
    const float* __restrict__ gk, float* __restrict__ rates,
    float* __restrict__ gateo, u32* __restrict__ fcnt)
{
  const int tid = threadIdx.x;
  if (blockIdx.x == 0 && tid == 0) fcnt[0] = 0;
  __shared__ float qs[4][1024];
  const int b4 = blockIdx.x * 4;
#pragma unroll
  for (int r = 0; r < 4; ++r) {
    const float4 qv = *(const float4*)(q + (size_t)(b4 + r) * 1024 + tid * 4);
    *(float4*)(&qs[r][tid * 4]) = qv;
  }
  __syncthreads();

  const int w = tid >> 6, j = tid & 63;
  const int b = b4 + w;
  const float* __restrict__ wc = win + j;
  float bufA[64], bufB[64];
#pragma unroll
  for (int i = 0; i < 64; ++i) bufA[i] = wc[i * 64];
  float c = 0.f;
#pragma unroll
  for (int ch = 0; ch < 8; ++ch) {
#pragma unroll
    for (int i = 0; i < 64; ++i)
      bufB[i] = wc[((2 * ch + 1) * 64 + i) * 64];
#pragma unroll
    for (int i = 0; i < 64; ++i)
      c = __builtin_fmaf(qs[w][2 * ch * 64 + i], bufA[i], c);
    if (ch < 7) {
#pragma unroll
      for (int i = 0; i < 64; ++i)
        bufA[i] = wc[((2 * ch + 2) * 64 + i) * 64];
    }
#pragma unroll
    for (int i = 0; i < 64; ++i)
      c = __builtin_fmaf(qs[w][(2 * ch + 1) * 64 + i], bufB[i], c);
  }
  const float x = c;
  float r;
  if (x >= 0.f) r = __fdiv_rn(1.f, __fadd_rn(1.f, expf(-x)));
  else { const float ex = expf(x); r = __fdiv_rn(ex, __fadd_rn(1.f, ex)); }
  rates[b * 64 + j] = r;

  const int jj = j & 15;
  float l = 0.f;
  for (int dd = 0; dd < 64; ++dd) {
    const float xv = __shfl(x, dd, 64);
    l = __builtin_fmaf(xv, gk[dd * 16 + jj], l);
  }
  l = __fadd_rn(l, gbias[jj]);
  l = __fdiv_rn(l, temp[0]);
  float m = l;
  for (int off = 1; off < 16; off <<= 1) m = fmaxf(m, __shfl_xor(m, off, 16));
  const float p = expf(__fsub_rn(l, m));
  float s = p;
  for (int off = 1; off < 16; off <<= 1) s += __shfl_xor(s, off, 16);
  if (j < 16) gateo[b * 16 + j] = __fdiv_rn(p, s);
}

// ---------- K1: fused {expert split | poisson spikes} ------------------------
__global__ __launch_bounds__(256) void k_prep(
    const float* __restrict__ ex, u16* __restrict__ wsp,
    const float* __restrict__ rates, u16* __restrict__ spk, u32 bk0, u32 bk1)
{
  if (blockIdx.x < 256) {
    const int e = blockIdx.x >> 4, hb = blockIdx.x & 15;
    const int tl = threadIdx.x & 63, tg = threadIdx.x >> 6;
    __shared__ float tile[64][65];
#pragma unroll
    for (int r = 0; r < 16; ++r) {
      const int d = r * 4 + tg;
      tile[d][tl] = ex[((size_t)e * 64 + d) * 1024 + hb * 64 + tl];
    }
    __syncthreads();
#pragma unroll
    for (int r = 0; r < 16; ++r) {
      const int hl = r * 4 + tg;
      const size_t o = ((size_t)e * 1024 + hb * 64 + hl) * 64 + tl;
      wsp[o] = f2bf(tile[tl][hl] * 0.05f);           // fold leak = DT/TAU
    }
  } else {
    const u32 g = (blockIdx.x - 256) * 256u + threadIdx.x;
    u32 o0, o1;
    tf2x32(bk0, bk1, 0u, g, &o0, &o1);               // 64-bit counter (0, g)
    const u32 bits = o0 ^ o1;
    const float r = rates[g & 16383u];
    const float u = __uint_as_float((bits >> 9) | 0x3f800000u) - 1.0f;
    spk[g] = (u < r) ? (u16)0x3F80 : (u16)0;
  }
}

// ---------- K2: approx LIF scan -- branchless, dmin flags, big budget -------
// wave = 32b x 64h (2 b-subtiles x 4 nt): 16 MFMA + ~210 VALU per t, no
// branches, no SALU exec dances, no per-t flag bits (dmin=fmin chain, 1 inst).
// (256,2): 512 blocks = exactly 2/CU, ALL resident, 256-reg budget (no AGPR
// churn on acc reads -- R7-R9 pathology). Single bf16 weights (R9-verified,
// drift << FLAG_DELTA=2e-2; flagged elems ~0-3 globally, exact-patched).
// grid (8 hblk, 4 bblk, 16 e) = 512 blocks, 256 thr.
__global__ __launch_bounds__(256, 2) void k_lif(
    const u16* __restrict__ spk, const u16* __restrict__ wsp,
    u8* __restrict__ cnt, u32* __restrict__ fcnt, u32* __restrict__ flist)
{
  const int hblk = blockIdx.x, bblk = blockIdx.y, e = blockIdx.z;
  const int tid = threadIdx.x;
  const int w = tid >> 6, lane = tid & 63;
  const int wb = w & 1, wh = w >> 1;
  const int lr = lane & 15, lg = lane >> 4;
  const int b0w = bblk * 64 + wb * 32;               // wave's 32-b base
  const int h0w = hblk * 128 + wh * 64;              // wave's 64-h base

  // B frags: wsp[e][h][d]; lane: n = lr (h), k = kc*32 + lg*8 + j
#define FRAG(NT, KC) (*(const bf16x8*)(wsp + \
    ((size_t)e * 1024 + h0w + (NT) * 16 + lr) * 64 + (KC) * 32 + lg * 8))
  const bf16x8 F00 = FRAG(0, 0), F01 = FRAG(0, 1);
  const bf16x8 F10 = FRAG(1, 0), F11 = FRAG(1, 1);
  const bf16x8 F20 = FRAG(2, 0), F21 = FRAG(2, 1);
  const bf16x8 F30 = FRAG(3, 0), F31 = FRAG(3, 1);
#undef FRAG

  f32x4 A00 = (f32x4){0.f, 0.f, 0.f, 0.f};
  f32x4 A01 = A00, A02 = A00, A03 = A00;             // bsub0, nt0..3
  f32x4 A10 = A00, A11 = A00, A12 = A00, A13 = A00;  // bsub1
  const f32x4 DI = (f32x4){1e30f, 1e30f, 1e30f, 1e30f};
  f32x4 D00 = DI, D01 = DI, D02 = DI, D03 = DI;      // per-elem min|nv-0.5|
  f32x4 D10 = DI, D11 = DI, D12 = DI, D13 = DI;
  u32 C00 = 0, C01 = 0, C02 = 0, C03 = 0;            // byte-packed counts
  u32 C10 = 0, C11 = 0, C12 = 0, C13 = 0;

  const u16* ab0 = spk + (size_t)(b0w + lr) * 64 + lg * 8;
  const u16* ab1 = spk + (size_t)(b0w + 16 + lr) * 64 + lg * 8;
  bf16x8 a0 = *(const bf16x8*)(ab0);
  bf16x8 a1 = *(const bf16x8*)(ab0 + 32);
  bf16x8 a2 = *(const bf16x8*)(ab1);
  bf16x8 a3 = *(const bf16x8*)(ab1 + 32);

#define MF(A, B, C) __builtin_amdgcn_mfma_f32_16x16x32_bf16((A), (B), (C), 0, 0, 0)

  // tt = nv-0.5: sign(tt) == (nv>=0.5) exactly (Sterbenz on [0.25,1], sign
  // preserved outside). dmin via v_min_f32 with free abs modifier. No branch.
#define PR(VAL, CW, DMC, I) {                        \
    const float tt = (VAL) - 0.5f;                   \
    (DMC) = fminf((DMC), __builtin_fabsf(tt));       \
    const bool sp = (tt >= 0.f);                     \
    (CW) += ((u32)sp) << (8 * (I));                  \
    (VAL) = sp ? 0.f : (VAL); }

#define STEPQ(ACC, CW, DM, AX, AY, FL_, FH_) {       \
    f32x4 acc = (ACC) * 0.95f;                       \
    acc = MF((AX), (FL_), acc);                      \
    acc = MF((AY), (FH_), acc);                      \
    PR(acc.x, (CW), DM.x, 0)                         \
    PR(acc.y, (CW), DM.y, 1)                         \
    PR(acc.z, (CW), DM.z, 2)                         \
    PR(acc.w, (CW), DM.w, 3)                         \
    (ACC) = acc; }

  for (int t = 0; t < 20; ++t) {
    const int tn = (t < 19) ? t + 1 : 19;            // prefetch next (clamped)
    const bf16x8 n0 = *(const bf16x8*)(ab0 + (size_t)tn * 16384);
    const bf16x8 n1 = *(const bf16x8*)(ab0 + (size_t)tn * 16384 + 32);
    const bf16x8 n2 = *(const bf16x8*)(ab1 + (size_t)tn * 16384);
    const bf16x8 n3 = *(const bf16x8*)(ab1 + (size_t)tn * 16384 + 32);
    STEPQ(A00, C00, D00, a0, a1, F00, F01)
    STEPQ(A01, C01, D01, a0, a1, F10, F11)
    STEPQ(A02, C02, D02, a0, a1, F20, F21)
    STEPQ(A03, C03, D03, a0, a1, F30, F31)
    STEPQ(A10, C10, D10, a2, a3, F00, F01)
    STEPQ(A11, C11, D11, a2, a3, F10, F11)
    STEPQ(A12, C12, D12, a2, a3, F20, F21)
    STEPQ(A13, C13, D13, a2, a3, F30, F31)
    a0 = n0; a1 = n1; a2 = n2; a3 = n3;
  }
#undef STEPQ
#undef PR
#undef MF

  // flag extraction (once, after the t-loop): bit k = bsub*16 + nt*4 + i
  u32 fl = 0;
#define FLG(DMC, K) fl |= ((DMC) < FLAG_DELTA) ? (1u << (K)) : 0u;
  FLG(D00.x, 0)  FLG(D00.y, 1)  FLG(D00.z, 2)  FLG(D00.w, 3)
  FLG(D01.x, 4)  FLG(D01.y, 5)  FLG(D01.z, 6)  FLG(D01.w, 7)
  FLG(D02.x, 8)  FLG(D02.y, 9)  FLG(D02.z, 10) FLG(D02.w, 11)
  FLG(D03.x, 12) FLG(D03.y, 13) FLG(D03.z, 14) FLG(D03.w, 15)
  FLG(D10.x, 16) FLG(D10.y, 17) FLG(D10.z, 18) FLG(D10.w, 19)
  FLG(D11.x, 20) FLG(D11.y, 21) FLG(D11.z, 22) FLG(D11.w, 23)
  FLG(D12.x, 24) FLG(D12.y, 25) FLG(D12.z, 26) FLG(D12.w, 27)
  FLG(D13.x, 28) FLG(D13.y, 29) FLG(D13.z, 30) FLG(D13.w, 31)
#undef FLG

  // C/D layout: col = lane&15 (h), row = (lane>>4)*4 + reg (b)
  const u32 cws[8] = {C00, C01, C02, C03, C10, C11, C12, C13};
#pragma unroll
  for (int bs = 0; bs < 2; ++bs)
#pragma unroll
    for (int nt = 0; nt < 4; ++nt) {
      const int h = h0w + nt * 16 + lr;
      const u32 cw = cws[bs * 4 + nt];
#pragma unroll
      for (int i = 0; i < 4; ++i) {
        const int b = b0w + bs * 16 + lg * 4 + i;
        cnt[((size_t)e * 256 + b) * 1024 + h] = (u8)((cw >> (8 * i)) & 0xFFu);
      }
    }

  // wave-aggregated flag append: <=1 atomic per wave, skipped if none
  const u32 myc = (u32)__builtin_popcount((int)fl);
  u32 pre = myc;
#pragma unroll
  for (int off = 1; off < 64; off <<= 1) {
    const u32 xx = __shfl_up(pre, off, 64);
    if (lane >= off) pre += xx;
  }
  const u32 tot = __shfl(pre, 63, 64);
  if (tot) {
    u32 base = 0;
    if (lane == 63) base = atomicAdd(fcnt, tot);
    base = __shfl(base, 63, 64);
    u32 slot = base + pre - myc;
    if (fl) {
      for (int k = 0; k < 32; ++k)
        if ((fl >> k) & 1u) {
          const int bs = k >> 4, nt = (k >> 2) & 3, i = k & 3;
          const int b = b0w + bs * 16 + lg * 4 + i;
          const int h = h0w + nt * 16 + lr;
          if (slot < FLAG_CAP)
            flist[slot] = ((u32)e << 18) | ((u32)b << 10) | (u32)h;
          slot++;
        }
    }
  }
}

// ---------- K2b: exact recompute of flagged elements (round-2 math) ---------
// weights straight from ex (stride-1024 loads; flags ~0-3 so cost ~nil)
__global__ __launch_bounds__(256) void k_fix(
    const u16* __restrict__ spk, const float* __restrict__ ex,
    const u32* __restrict__ fcnt, const u32* __restrict__ flist,
    u8* __restrict__ cnt)
{
  u32 n = fcnt[0];
  if (n > FLAG_CAP) n = FLAG_CAP;
  for (u32 i = blockIdx.x * 256u + threadIdx.x; i < n; i += 65536u) {
    const u32 p = flist[i];
    const int h = (int)(p & 1023u), b = (int)((p >> 10) & 255u), e = (int)(p >> 18);
    float wr[64];
#pragma unroll
    for (int d = 0; d < 64; ++d)
      wr[d] = ex[((size_t)e * 64 + d) * 1024 + h];
    float v = 0.f;
    int c = 0;
    for (int t = 0; t < 20; ++t) {
      const uint4* __restrict__ sr = (const uint4*)(spk + (size_t)(t * 256 + b) * 64);
      float cc = 0.f;
#pragma unroll
      for (int w8 = 0; w8 < 8; ++w8) {
        const uint4 sv = sr[w8];
        cc = __builtin_fmaf(__uint_as_float(sv.x << 16),         wr[w8 * 8 + 0], cc);
        cc = __builtin_fmaf(__uint_as_float(sv.x & 0xFFFF0000u), wr[w8 * 8 + 1], cc);
        cc = __builtin_fmaf(__uint_as_float(sv.y << 16),         wr[w8 * 8 + 2], cc);
        cc = __builtin_fmaf(__uint_as_float(sv.y & 0xFFFF0000u), wr[w8 * 8 + 3], cc);
        cc = __builtin_fmaf(__uint_as_float(sv.z << 16),         wr[w8 * 8 + 4], cc);
        cc = __builtin_fmaf(__uint_as_float(sv.z & 0xFFFF0000u), wr[w8 * 8 + 5], cc);
        cc = __builtin_fmaf(__uint_as_float(sv.w << 16),         wr[w8 * 8 + 6], cc);
        cc = __builtin_fmaf(__uint_as_float(sv.w & 0xFFFF0000u), wr[w8 * 8 + 7], cc);
      }
      const float nv = __fadd_rn(v, __fmul_rn(__fsub_rn(cc, v), 0.05f));
      if (nv >= 0.5f) { c++; v = 0.f; } else v = nv;
    }
    cnt[((size_t)e * 256 + b) * 1024 + h] = (u8)c;
  }
}

// ---------- K3: out[b,h] = ascending-e fma chain of (cnt/20)*p --------------
__global__ __launch_bounds__(256) void k_combine(
    const u8* __restrict__ cnt, const float* __restrict__ gateo,
    float* __restrict__ out)
{
  const int idx = blockIdx.x * 256 + threadIdx.x;   // [0, 65536)
  const int b = idx >> 8, hq = idx & 255;
  const int h0 = hq * 4;
  float s0 = 0.f, s1 = 0.f, s2 = 0.f, s3 = 0.f;
#pragma unroll
  for (int e = 0; e < 16; ++e) {
    const uchar4 cv = *(const uchar4*)(cnt + ((size_t)e * 256 + b) * 1024 + h0);
    const float g = gateo[b * 16 + e];
    s0 = __builtin_fmaf(__fdiv_rn((float)cv.x, 20.f), g, s0);
    s1 = __builtin_fmaf(__fdiv_rn((float)cv.y, 20.f), g, s1);
    s2 = __builtin_fmaf(__fdiv_rn((float)cv.z, 20.f), g, s2);
    s3 = __builtin_fmaf(__fdiv_rn((float)cv.w, 20.f), g, s3);
  }
  float4 o;
  o.x = s0; o.y = s1; o.z = s2; o.w = s3;
  *(float4*)(out + (size_t)b * 1024 + h0) = o;
}

// ---------- launch ----------------------------------------------------------
extern "C" void kernel_launch(void* const* d_in, const int* in_sizes, int n_in,
                              void* d_out, int out_size, void* d_ws, size_t ws_size,
                              hipStream_t stream)
{
  (void)in_sizes; (void)n_in; (void)out_size; (void)ws_size;
  const float* q     = (const float*)d_in[0];
  const float* gbias = (const float*)d_in[1];
  const float* temp  = (const float*)d_in[2];
  const float* win   = (const float*)d_in[3];
  const float* ex    = (const float*)d_in[4];
  const float* gk    = (const float*)d_in[5];
  float* out = (float*)d_out;

  char* ws = (char*)d_ws;
  u16*  spk   = (u16*)(ws + 0);            // [20][256][64] bf16    655360 B
  float* rates = (float*)(ws + 655360);    // [256][64] f32          65536 B
  float* gateo = (float*)(ws + 720896);    // [256][16] f32          16384 B
  u16*  wsp   = (u16*)(ws + 737280);       // [16][1024][64] bf16  2097152 B
  u8*   cnt   = (u8*)(ws + 2834432);       // [16][256][1024] u8   4194304 B
  u32*  fcnt  = (u32*)(ws + 7028736);      // counter                  4 B
  u32*  flist = (u32*)(ws + 7029760);      // [262144] u32         1048576 B
                                           // total: 8078336 B

  // bern_key = jax.random.split(jax.random.key(0))[1], computed on host
  u32 bk0, bk1;
  tf2x32(0u, 0u, 0u, 1u, &bk0, &bk1);

  k_gate<<<64, 256, 0, stream>>>(q, win, gbias, temp, gk, rates, gateo, fcnt);
  k_prep<<<256 + 1280, 256, 0, stream>>>(ex, wsp, rates, spk, bk0, bk1);
  k_lif<<<dim3(8, 4, 16), 256, 0, stream>>>(spk, wsp, cnt, fcnt, flist);
  k_fix<<<256, 256, 0, stream>>>(spk, ex, fcnt, flist, cnt);
  k_combine<<<256, 256, 0, stream>>>(cnt, gateo, out);
}